// Round 1
// baseline (647.926 us; speedup 1.0000x reference)
//
#include <hip/hip_runtime.h>

#define B_  512
#define D_  256
#define O_  256
#define H2_ 1024

typedef __attribute__((ext_vector_type(4))) float  f32x4;
typedef __attribute__((ext_vector_type(8))) short  short8;
typedef __attribute__((ext_vector_type(4))) short  short4v;
typedef unsigned short ushort_t;

union S8u  { short4v v; unsigned u[2]; };
union S16u { short8  v; unsigned u[4]; };

// fp32 -> bf16 round-to-nearest-even on raw bits (finite inputs only)
__device__ __forceinline__ unsigned f32_bf16(float x) {
  unsigned u = __builtin_bit_cast(unsigned, x);
  return (u + 0x7fffu + ((u >> 16) & 1u)) >> 16;
}
__device__ __forceinline__ unsigned cvt_pk_bf16(float a, float b) {
  return f32_bf16(a) | (f32_bf16(b) << 16);
}

// async global->LDS, 16B per lane, wave-uniform LDS base + lane*16
__device__ __forceinline__ void gload_lds16(const void* g, void* l) {
  __builtin_amdgcn_global_load_lds(
      (const __attribute__((address_space(1))) unsigned*)g,
      (__attribute__((address_space(3))) unsigned*)l, 16, 0, 0);
}

// ---------------------------------------------------------------------------
// Generic small GEMM: C[M,N] = act(A[M,K] @ B[N,K]^T + bias[N]); fp32 in/out,
// bf16 MFMA inside. 64x64 tile per block, 256 threads = 4 waves, each wave a
// 32x32 quadrant (2x2 of 16x16x32 mfma), BK=64. All dims multiples of 64.
// (unchanged — verified passing)
// ---------------------------------------------------------------------------
template <int RELU>
__global__ __launch_bounds__(256)
void gemm_bt64(const float* __restrict__ A, const float* __restrict__ Bm,
               const float* __restrict__ bias, float* __restrict__ C,
               int M, int N, int K) {
  __shared__ __align__(16) short As[64][72];
  __shared__ __align__(16) short Bs[64][72];
  const int t    = threadIdx.x;
  const int m0   = blockIdx.y * 64;
  const int n0   = blockIdx.x * 64;
  const int f4c  = t & 15;
  const int rg   = t >> 4;
  const int lane = t & 63;
  const int w    = t >> 6;
  const int wm   = (w & 1) * 32;
  const int wn   = (w >> 1) * 32;
  const int lr   = lane & 15;
  const int lq   = lane >> 4;

  f32x4 acc[2][2];
  #pragma unroll
  for (int i = 0; i < 2; ++i)
    #pragma unroll
    for (int j = 0; j < 2; ++j) acc[i][j] = f32x4{0.f, 0.f, 0.f, 0.f};

  for (int k0 = 0; k0 < K; k0 += 64) {
    #pragma unroll
    for (int j = 0; j < 4; ++j) {
      int r = rg + 16 * j;
      f32x4 av = *(const f32x4*)(A  + (size_t)(m0 + r) * K + k0 + f4c * 4);
      f32x4 bv = *(const f32x4*)(Bm + (size_t)(n0 + r) * K + k0 + f4c * 4);
      S8u sa; sa.u[0] = cvt_pk_bf16(av.x, av.y); sa.u[1] = cvt_pk_bf16(av.z, av.w);
      S8u sb; sb.u[0] = cvt_pk_bf16(bv.x, bv.y); sb.u[1] = cvt_pk_bf16(bv.z, bv.w);
      *(short4v*)&As[r][f4c * 4] = sa.v;
      *(short4v*)&Bs[r][f4c * 4] = sb.v;
    }
    __syncthreads();
    #pragma unroll
    for (int ks = 0; ks < 2; ++ks) {
      short8 a0 = *(const short8*)&As[wm + lr     ][ks * 32 + lq * 8];
      short8 a1 = *(const short8*)&As[wm + 16 + lr][ks * 32 + lq * 8];
      short8 b0 = *(const short8*)&Bs[wn + lr     ][ks * 32 + lq * 8];
      short8 b1 = *(const short8*)&Bs[wn + 16 + lr][ks * 32 + lq * 8];
      acc[0][0] = __builtin_amdgcn_mfma_f32_16x16x32_bf16(a0, b0, acc[0][0], 0, 0, 0);
      acc[0][1] = __builtin_amdgcn_mfma_f32_16x16x32_bf16(a0, b1, acc[0][1], 0, 0, 0);
      acc[1][0] = __builtin_amdgcn_mfma_f32_16x16x32_bf16(a1, b0, acc[1][0], 0, 0, 0);
      acc[1][1] = __builtin_amdgcn_mfma_f32_16x16x32_bf16(a1, b1, acc[1][1], 0, 0, 0);
    }
    __syncthreads();
  }
  #pragma unroll
  for (int mi = 0; mi < 2; ++mi)
    #pragma unroll
    for (int ni = 0; ni < 2; ++ni)
      #pragma unroll
      for (int r = 0; r < 4; ++r) {
        int row = m0 + wm + mi * 16 + lq * 4 + r;
        int col = n0 + wn + ni * 16 + lr;
        float v = acc[mi][ni][r] + bias[col];
        if (RELU) v = fmaxf(v, 0.f);
        C[(size_t)row * N + col] = v;
      }
}

// ---------------------------------------------------------------------------
// out[b,o] += sum_d input[b,d] * b_d[d*O+o]   (one block per b row) (unchanged)
// ---------------------------------------------------------------------------
__global__ __launch_bounds__(256)
void bias_d_kernel(const float* __restrict__ inp, const float* __restrict__ b_d,
                   float* __restrict__ out) {
  const int b = blockIdx.x;
  const int o = threadIdx.x;
  const float* ir = inp + (size_t)b * D_;
  float s = 0.f;
  for (int d = 0; d < D_; ++d)
    s += ir[d] * b_d[(size_t)d * O_ + o];
  out[(size_t)b * O_ + o] += s;
}

// ---------------------------------------------------------------------------
// Bulk fp32 -> bf16 conversion, 8 elems/thread/iter, grid-stride. BW-bound.
// ---------------------------------------------------------------------------
__global__ __launch_bounds__(256)
void cvt_f32_bf16(const float* __restrict__ in, ushort_t* __restrict__ out, int n8) {
  for (size_t i = (size_t)blockIdx.x * 256 + threadIdx.x; i < (size_t)n8;
       i += (size_t)gridDim.x * 256) {
    const float* p = in + i * 8;
    f32x4 v0 = *(const f32x4*)p;
    f32x4 v1 = *(const f32x4*)(p + 4);
    S16u s;
    s.u[0] = cvt_pk_bf16(v0.x, v0.y);
    s.u[1] = cvt_pk_bf16(v0.z, v0.w);
    s.u[2] = cvt_pk_bf16(v1.x, v1.y);
    s.u[3] = cvt_pk_bf16(v1.z, v1.w);
    *(short8*)(out + i * 8) = s.v;
  }
}

// ---------------------------------------------------------------------------
// Stage B v2: pure-bf16 m97-style GEMM with global_load_lds staging.
//   For each d in the block's 4-d chunk:
//     acc[m,n] = sum_h x2b[m,h] * Wdb[(d*O+bn+n), h]   (16 k-iters of BK=64)
//     run[m,n] += input[m,d] * acc[m,n]                 (post-MFMA scale)
//   atomicAdd run into out.
// Grid (8,64) = 512 blocks, remapped so the 4 mt-blocks sharing a W_d slice
// satisfy lin % 8 == const -> same XCD -> slice fetched once through that L2.
// ---------------------------------------------------------------------------
__global__ __launch_bounds__(256, 2)
void stage_b2(const ushort_t* __restrict__ x2b, const float* __restrict__ inp,
              const ushort_t* __restrict__ Wdb, float* __restrict__ out) {
  __shared__ __align__(16) ushort_t As[128 * 64];   // linear: gload_lds needs it
  __shared__ __align__(16) ushort_t Bs[128 * 64];
  const int t    = threadIdx.x;
  const int lin  = blockIdx.x + 8 * blockIdx.y;     // 0..511, lin%8 = XCD
  const int mt   = lin >> 7;                        // 0..3 (same XCD across mt)
  const int g    = lin & 127;
  const int nt   = g & 1;
  const int y    = g >> 1;                          // 0..63
  const int bm   = mt * 128;
  const int bn   = nt * 128;
  const int d0   = y * 4;
  const int lane = t & 63;
  const int w    = t >> 6;
  const int wm   = (w & 1) * 64;
  const int wn   = (w >> 1) * 64;
  const int lr   = lane & 15;
  const int lq   = lane >> 4;
  // staging: wave w covers rows [w*32, w*32+32), 4 calls x 8 rows, 16B/lane
  const int srow = w * 32 + (lane >> 3);            // + c*8
  const int scol = (lane & 7) * 8;                  // bf16 elem offset in row

  f32x4 run[4][4];
  #pragma unroll
  for (int mi = 0; mi < 4; ++mi)
    #pragma unroll
    for (int ni = 0; ni < 4; ++ni) run[mi][ni] = f32x4{0.f, 0.f, 0.f, 0.f};

  for (int dl = 0; dl < 4; ++dl) {
    const int d = d0 + dl;
    const ushort_t* wrow = Wdb + (size_t)(d * O_ + bn) * H2_;

    f32x4 acc[4][4];
    #pragma unroll
    for (int mi = 0; mi < 4; ++mi)
      #pragma unroll
      for (int ni = 0; ni < 4; ++ni) acc[mi][ni] = f32x4{0.f, 0.f, 0.f, 0.f};

    for (int h0 = 0; h0 < H2_; h0 += 64) {
      #pragma unroll
      for (int c = 0; c < 4; ++c) {
        const int r = srow + c * 8;
        gload_lds16(x2b  + (size_t)(bm + r) * H2_ + h0 + scol,
                    &As[(w * 32 + c * 8) * 64]);
        gload_lds16(wrow + (size_t)r * H2_ + h0 + scol,
                    &Bs[(w * 32 + c * 8) * 64]);
      }
      __syncthreads();   // drains vmcnt -> LDS tiles complete
      #pragma unroll
      for (int ks = 0; ks < 2; ++ks) {
        short8 af[4], bfr[4];
        #pragma unroll
        for (int mi = 0; mi < 4; ++mi)
          af[mi] = *(const short8*)&As[(wm + mi * 16 + lr) * 64 + ks * 32 + lq * 8];
        #pragma unroll
        for (int ni = 0; ni < 4; ++ni)
          bfr[ni] = *(const short8*)&Bs[(wn + ni * 16 + lr) * 64 + ks * 32 + lq * 8];
        #pragma unroll
        for (int mi = 0; mi < 4; ++mi)
          #pragma unroll
          for (int ni = 0; ni < 4; ++ni)
            acc[mi][ni] = __builtin_amdgcn_mfma_f32_16x16x32_bf16(af[mi], bfr[ni],
                                                                  acc[mi][ni], 0, 0, 0);
      }
      __syncthreads();
    }

    // post-MFMA scale by input[row, d] into the running accumulator
    #pragma unroll
    for (int mi = 0; mi < 4; ++mi)
      #pragma unroll
      for (int r = 0; r < 4; ++r) {
        const float sc = inp[(size_t)(bm + wm + mi * 16 + lq * 4 + r) * D_ + d];
        #pragma unroll
        for (int ni = 0; ni < 4; ++ni)
          run[mi][ni][r] += sc * acc[mi][ni][r];
      }
  }

  #pragma unroll
  for (int mi = 0; mi < 4; ++mi)
    #pragma unroll
    for (int ni = 0; ni < 4; ++ni)
      #pragma unroll
      for (int r = 0; r < 4; ++r) {
        int row = bm + wm + mi * 16 + lq * 4 + r;
        int col = bn + wn + ni * 16 + lr;
        atomicAdd(out + (size_t)row * O_ + col, run[mi][ni][r]);
      }
}

// ---------------------------------------------------------------------------
// Fallback Stage B (previous verified version) for small workspaces.
// ---------------------------------------------------------------------------
__global__ __launch_bounds__(256, 2)
void stage_b_old(const float* __restrict__ x2, const float* __restrict__ inp,
                 const float* __restrict__ Wd, float* __restrict__ out) {
  __shared__ __align__(16) short As[128][72];
  __shared__ __align__(16) short Bs[128][72];
  const int t    = threadIdx.x;
  const int mt   = blockIdx.x >> 1;
  const int nt   = blockIdx.x & 1;
  const int d0   = blockIdx.y * 4;
  const int bm   = mt * 128;
  const int bn   = nt * 128;
  const int f4c  = t & 15;
  const int rg   = t >> 4;
  const int lane = t & 63;
  const int w    = t >> 6;
  const int wm   = (w & 1) * 64;
  const int wn   = (w >> 1) * 64;
  const int lr   = lane & 15;
  const int lq   = lane >> 4;

  f32x4 acc[4][4];
  #pragma unroll
  for (int mi = 0; mi < 4; ++mi)
    #pragma unroll
    for (int ni = 0; ni < 4; ++ni) acc[mi][ni] = f32x4{0.f, 0.f, 0.f, 0.f};

  for (int dl = 0; dl < 4; ++dl) {
    const int d = d0 + dl;
    float insc[8];
    #pragma unroll
    for (int j = 0; j < 8; ++j)
      insc[j] = inp[(size_t)(bm + rg + 16 * j) * D_ + d];
    const float* wbase = Wd + ((size_t)d * O_ + bn) * H2_;

    for (int h0 = 0; h0 < H2_; h0 += 64) {
      #pragma unroll
      for (int j = 0; j < 8; ++j) {
        int r = rg + 16 * j;
        f32x4 xv = *(const f32x4*)(x2 + (size_t)(bm + r) * H2_ + h0 + f4c * 4);
        float s = insc[j];
        S8u sa;
        sa.u[0] = cvt_pk_bf16(xv.x * s, xv.y * s);
        sa.u[1] = cvt_pk_bf16(xv.z * s, xv.w * s);
        *(short4v*)&As[r][f4c * 4] = sa.v;
        f32x4 wv = *(const f32x4*)(wbase + (size_t)r * H2_ + h0 + f4c * 4);
        S8u sb; sb.u[0] = cvt_pk_bf16(wv.x, wv.y); sb.u[1] = cvt_pk_bf16(wv.z, wv.w);
        *(short4v*)&Bs[r][f4c * 4] = sb.v;
      }
      __syncthreads();
      #pragma unroll
      for (int ks = 0; ks < 2; ++ks) {
        short8 af[4], bfr[4];
        #pragma unroll
        for (int mi = 0; mi < 4; ++mi)
          af[mi] = *(const short8*)&As[wm + mi * 16 + lr][ks * 32 + lq * 8];
        #pragma unroll
        for (int ni = 0; ni < 4; ++ni)
          bfr[ni] = *(const short8*)&Bs[wn + ni * 16 + lr][ks * 32 + lq * 8];
        #pragma unroll
        for (int mi = 0; mi < 4; ++mi)
          #pragma unroll
          for (int ni = 0; ni < 4; ++ni)
            acc[mi][ni] = __builtin_amdgcn_mfma_f32_16x16x32_bf16(af[mi], bfr[ni],
                                                                  acc[mi][ni], 0, 0, 0);
      }
      __syncthreads();
    }
  }

  #pragma unroll
  for (int mi = 0; mi < 4; ++mi)
    #pragma unroll
    for (int ni = 0; ni < 4; ++ni)
      #pragma unroll
      for (int r = 0; r < 4; ++r) {
        int row = bm + wm + mi * 16 + lq * 4 + r;
        int col = bn + wn + ni * 16 + lr;
        atomicAdd(out + (size_t)row * O_ + col, acc[mi][ni][r]);
      }
}

extern "C" void kernel_launch(void* const* d_in, const int* in_sizes, int n_in,
                              void* d_out, int out_size, void* d_ws, size_t ws_size,
                              hipStream_t stream) {
  const float* input = (const float*)d_in[0];   // [512,256]
  const float* nanf  = (const float*)d_in[1];   // [512,256]
  const float* W_in  = (const float*)d_in[3];   // [512,256]
  const float* b_in  = (const float*)d_in[4];
  const float* W_h1  = (const float*)d_in[5];   // [1024,512]
  const float* b_h1  = (const float*)d_in[6];
  const float* W_h2  = (const float*)d_in[7];   // [1024,1024]
  const float* b_h2  = (const float*)d_in[8];
  const float* W_d   = (const float*)d_in[9];   // [65536,1024]
  const float* b_d   = (const float*)d_in[10];  // [65536]
  const float* W_b   = (const float*)d_in[11];  // [256,1024]
  const float* b_b   = (const float*)d_in[12];  // [256]
  float* out = (float*)d_out;                   // [512,256]

  float* x0 = (float*)d_ws;                     // [512,512]   1 MB
  float* x1 = x0 + 512 * 512;                   // [512,1024]  2 MB
  float* x2 = x1 + 512 * 1024;                  // [512,1024]  2 MB
  ushort_t* x2b = (ushort_t*)(x2 + 512 * 1024); // [512,1024] bf16, 1 MB
  ushort_t* Wdb = (ushort_t*)((char*)d_ws + 6ull * 1024 * 1024); // 128 MiB
  const size_t need = 6ull * 1024 * 1024 + 134217728ull;
  const bool fast = ws_size >= need;

  // W_d bf16 pre-conversion first: longest independent pole
  if (fast)
    cvt_f32_bf16<<<2048, 256, 0, stream>>>(W_d, Wdb, 65536 * 1024 / 8);

  // Stage A: MLP (~2 GFLOP total)
  gemm_bt64<1><<<dim3(512 / 64, 512 / 64), 256, 0, stream>>>(nanf, W_in, b_in, x0, 512, 512, 256);
  gemm_bt64<1><<<dim3(1024 / 64, 512 / 64), 256, 0, stream>>>(x0, W_h1, b_h1, x1, 512, 1024, 512);
  gemm_bt64<1><<<dim3(1024 / 64, 512 / 64), 256, 0, stream>>>(x1, W_h2, b_h2, x2, 512, 1024, 1024);
  if (fast)
    cvt_f32_bf16<<<256, 256, 0, stream>>>(x2, x2b, 512 * 1024 / 8);
  // out = x2 @ W_b^T + b_b   (comp_b, overwrites poisoned d_out)
  gemm_bt64<0><<<dim3(256 / 64, 512 / 64), 256, 0, stream>>>(x2, W_b, b_b, out, 512, 256, 1024);
  // out += input @ reshape(b_d, [D,O])
  bias_d_kernel<<<512, 256, 0, stream>>>(input, b_d, out);
  // Stage B: the fused 68.7 GFLOP bilinear contraction
  if (fast)
    stage_b2<<<dim3(8, 64), 256, 0, stream>>>(x2b, input, Wdb, out);
  else
    stage_b_old<<<dim3(8, 64), 256, 0, stream>>>(x2, input, W_d, out);
}

// Round 2
// 531.689 us; speedup vs baseline: 1.2186x; 1.2186x over previous
//
#include <hip/hip_runtime.h>

#define B_  512
#define D_  256
#define O_  256
#define H2_ 1024

typedef __attribute__((ext_vector_type(4))) float  f32x4;
typedef __attribute__((ext_vector_type(8))) short  short8;
typedef __attribute__((ext_vector_type(4))) short  short4v;
typedef unsigned short ushort_t;

union S8u  { short4v v; unsigned u[2]; };
union S16u { short8  v; unsigned u[4]; };

// fp32 -> bf16 round-to-nearest-even on raw bits (finite inputs only)
__device__ __forceinline__ unsigned f32_bf16(float x) {
  unsigned u = __builtin_bit_cast(unsigned, x);
  return (u + 0x7fffu + ((u >> 16) & 1u)) >> 16;
}
__device__ __forceinline__ unsigned cvt_pk_bf16(float a, float b) {
  return f32_bf16(a) | (f32_bf16(b) << 16);
}

// async global->LDS, 16B per lane, wave-uniform LDS base + lane*16
__device__ __forceinline__ void gload_lds16(const void* g, void* l) {
  __builtin_amdgcn_global_load_lds(
      (const __attribute__((address_space(1))) unsigned*)g,
      (__attribute__((address_space(3))) unsigned*)l, 16, 0, 0);
}

// ---------------------------------------------------------------------------
// Generic small GEMM: C[M,N] = act(A[M,K] @ B[N,K]^T + bias[N]); fp32 in/out,
// bf16 MFMA inside. 64x64 tile per block, 256 threads = 4 waves, each wave a
// 32x32 quadrant (2x2 of 16x16x32 mfma), BK=64. (unchanged — verified passing)
// ---------------------------------------------------------------------------
template <int RELU>
__global__ __launch_bounds__(256)
void gemm_bt64(const float* __restrict__ A, const float* __restrict__ Bm,
               const float* __restrict__ bias, float* __restrict__ C,
               int M, int N, int K) {
  __shared__ __align__(16) short As[64][72];
  __shared__ __align__(16) short Bs[64][72];
  const int t    = threadIdx.x;
  const int m0   = blockIdx.y * 64;
  const int n0   = blockIdx.x * 64;
  const int f4c  = t & 15;
  const int rg   = t >> 4;
  const int lane = t & 63;
  const int w    = t >> 6;
  const int wm   = (w & 1) * 32;
  const int wn   = (w >> 1) * 32;
  const int lr   = lane & 15;
  const int lq   = lane >> 4;

  f32x4 acc[2][2];
  #pragma unroll
  for (int i = 0; i < 2; ++i)
    #pragma unroll
    for (int j = 0; j < 2; ++j) acc[i][j] = f32x4{0.f, 0.f, 0.f, 0.f};

  for (int k0 = 0; k0 < K; k0 += 64) {
    #pragma unroll
    for (int j = 0; j < 4; ++j) {
      int r = rg + 16 * j;
      f32x4 av = *(const f32x4*)(A  + (size_t)(m0 + r) * K + k0 + f4c * 4);
      f32x4 bv = *(const f32x4*)(Bm + (size_t)(n0 + r) * K + k0 + f4c * 4);
      S8u sa; sa.u[0] = cvt_pk_bf16(av.x, av.y); sa.u[1] = cvt_pk_bf16(av.z, av.w);
      S8u sb; sb.u[0] = cvt_pk_bf16(bv.x, bv.y); sb.u[1] = cvt_pk_bf16(bv.z, bv.w);
      *(short4v*)&As[r][f4c * 4] = sa.v;
      *(short4v*)&Bs[r][f4c * 4] = sb.v;
    }
    __syncthreads();
    #pragma unroll
    for (int ks = 0; ks < 2; ++ks) {
      short8 a0 = *(const short8*)&As[wm + lr     ][ks * 32 + lq * 8];
      short8 a1 = *(const short8*)&As[wm + 16 + lr][ks * 32 + lq * 8];
      short8 b0 = *(const short8*)&Bs[wn + lr     ][ks * 32 + lq * 8];
      short8 b1 = *(const short8*)&Bs[wn + 16 + lr][ks * 32 + lq * 8];
      acc[0][0] = __builtin_amdgcn_mfma_f32_16x16x32_bf16(a0, b0, acc[0][0], 0, 0, 0);
      acc[0][1] = __builtin_amdgcn_mfma_f32_16x16x32_bf16(a0, b1, acc[0][1], 0, 0, 0);
      acc[1][0] = __builtin_amdgcn_mfma_f32_16x16x32_bf16(a1, b0, acc[1][0], 0, 0, 0);
      acc[1][1] = __builtin_amdgcn_mfma_f32_16x16x32_bf16(a1, b1, acc[1][1], 0, 0, 0);
    }
    __syncthreads();
  }
  #pragma unroll
  for (int mi = 0; mi < 2; ++mi)
    #pragma unroll
    for (int ni = 0; ni < 2; ++ni)
      #pragma unroll
      for (int r = 0; r < 4; ++r) {
        int row = m0 + wm + mi * 16 + lq * 4 + r;
        int col = n0 + wn + ni * 16 + lr;
        float v = acc[mi][ni][r] + bias[col];
        if (RELU) v = fmaxf(v, 0.f);
        C[(size_t)row * N + col] = v;
      }
}

// ---------------------------------------------------------------------------
// Bulk fp32 -> bf16 conversion (used for x2 only now; 1 MB out, ~2 us)
// ---------------------------------------------------------------------------
__global__ __launch_bounds__(256)
void cvt_f32_bf16(const float* __restrict__ in, ushort_t* __restrict__ out, int n8) {
  for (size_t i = (size_t)blockIdx.x * 256 + threadIdx.x; i < (size_t)n8;
       i += (size_t)gridDim.x * 256) {
    const float* p = in + i * 8;
    f32x4 v0 = *(const f32x4*)p;
    f32x4 v1 = *(const f32x4*)(p + 4);
    S16u s;
    s.u[0] = cvt_pk_bf16(v0.x, v0.y);
    s.u[1] = cvt_pk_bf16(v0.z, v0.w);
    s.u[2] = cvt_pk_bf16(v1.x, v1.y);
    s.u[3] = cvt_pk_bf16(v1.z, v1.w);
    *(short8*)(out + i * 8) = s.v;
  }
}

// out := 0  (512 KB, pre-stage_b3; all contributions atomicAdd afterwards)
__global__ __launch_bounds__(256)
void zero_out(float* __restrict__ p) {
  ((f32x4*)p)[(size_t)blockIdx.x * 256 + threadIdx.x] = f32x4{0.f, 0.f, 0.f, 0.f};
}

// ---------------------------------------------------------------------------
// Stage B v3: fully fused bilinear contraction + comp_b + bias_d + b_b.
//   out[b,o] = sum_d input[b,d]*( x2@W_d[d]^T + b_d[d] ) + x2@W_b^T + b_b
// Per block (mt,nt,y): 128x128 out tile, d-chunk [4y,4y+4). W_d read as fp32
// (no pre-conversion pass: 256 MB once = the HBM floor), converted to bf16 in
// registers during staging (VALU slack: kernel is memory-paced).
// A (x2 bf16, L2-resident) via global_load_lds with pre-swizzled source;
// B reg-staged; LDS XOR-swizzled (slot ^= row&7) to kill the 16-way
// ds_read_b128 bank conflict of a 128B-stride row-major tile (T2 / rule 21).
// Double-buffered, ONE barrier per k-iter, prefetch issued during compute
// (T14): the vmcnt(0) drain before the barrier lands after a full MFMA phase.
// comp_b distributed as K=128 chunks over y<8 blocks (scale=1, +3% on 1/8 of
// blocks); b_d folded pre-scale; b_b added by y==0. Split-d partials
// atomicAdd into zeroed out. XCD decode: the 4 mt-siblings sharing W rows
// have identical lin%8 -> same XCD -> W slice served once per XCD L2.
// ---------------------------------------------------------------------------
__global__ __launch_bounds__(256, 2)
void stage_b3(const ushort_t* __restrict__ x2b, const float* __restrict__ inp,
              const float* __restrict__ Wd, const float* __restrict__ bd,
              const float* __restrict__ Wb, const float* __restrict__ bbias,
              float* __restrict__ out) {
  __shared__ __align__(16) ushort_t As[2][128 * 64];
  __shared__ __align__(16) ushort_t Bs[2][128 * 64];
  const int t    = threadIdx.x;
  const int lin  = blockIdx.x + 8 * blockIdx.y;
  const int mt   = lin >> 7;
  const int g    = lin & 127;
  const int nt   = g & 1;
  const int y    = g >> 1;
  const int bm   = mt * 128;
  const int bn   = nt * 128;
  const int d0   = y * 4;
  const int lane = t & 63;
  const int w    = t >> 6;
  const int wm   = (w & 1) * 64;
  const int wn   = (w >> 1) * 64;
  const int lr   = lane & 15;
  const int lq   = lane >> 4;
  // A staging: call c stages rows w*32+c*8+arow; LDS linear, global pre-swizzled
  const int arow = lane >> 3;                 // 0..7 within the 8-row group
  const int acg  = (lane & 7) ^ arow;         // swizzled global col-group
  // B staging: thread covers rows rr+32j (j=0..3), col-group c8 -> slot bslot
  const int rr    = t >> 3;                   // 0..31
  const int c8    = t & 7;
  const int bslot = c8 ^ (rr & 7);
  // frag reads: logical 16B slot (ks*4+lq), stored at slot ^ (row&7)
  const int rsw  = lr & 7;

  const int NIT = (y < 8) ? 66 : 64;          // y<8: +2 iters of comp_b chunk

  f32x4 run[4][4], acc[4][4];
  #pragma unroll
  for (int mi = 0; mi < 4; ++mi)
    #pragma unroll
    for (int ni = 0; ni < 4; ++ni) {
      run[mi][ni] = f32x4{0.f, 0.f, 0.f, 0.f};
      acc[mi][ni] = f32x4{0.f, 0.f, 0.f, 0.f};
    }

  f32x4 breg[8];

  auto a_src = [&](int it) -> const ushort_t* {
    int h0 = (it < 64) ? ((it & 15) * 64) : (y * 128 + (it - 64) * 64);
    return x2b + (size_t)bm * H2_ + h0;
  };
  auto b_src = [&](int it) -> const float* {
    if (it < 64) {
      int d = d0 + (it >> 4);
      return Wd + ((size_t)(d * O_ + bn)) * H2_ + (it & 15) * 64;
    }
    return Wb + (size_t)bn * H2_ + y * 128 + (it - 64) * 64;
  };
  auto stage_a = [&](int it, int bf) {
    const ushort_t* ab = a_src(it);
    #pragma unroll
    for (int c = 0; c < 4; ++c) {
      int r0 = w * 32 + c * 8;
      gload_lds16(ab + (size_t)(r0 + arow) * H2_ + acg * 8, &As[bf][r0 * 64]);
    }
  };
  auto load_b = [&](int it) {
    const float* bp = b_src(it);
    #pragma unroll
    for (int j = 0; j < 4; ++j) {
      const float* p = bp + (size_t)(rr + 32 * j) * H2_ + c8 * 8;
      breg[2 * j]     = *(const f32x4*)p;
      breg[2 * j + 1] = *(const f32x4*)(p + 4);
    }
  };
  auto write_b = [&](int bf) {
    #pragma unroll
    for (int j = 0; j < 4; ++j) {
      S16u s;
      s.u[0] = cvt_pk_bf16(breg[2 * j].x,     breg[2 * j].y);
      s.u[1] = cvt_pk_bf16(breg[2 * j].z,     breg[2 * j].w);
      s.u[2] = cvt_pk_bf16(breg[2 * j + 1].x, breg[2 * j + 1].y);
      s.u[3] = cvt_pk_bf16(breg[2 * j + 1].z, breg[2 * j + 1].w);
      *(short8*)&Bs[bf][(rr + 32 * j) * 64 + bslot * 8] = s.v;
    }
  };

  int buf = 0;
  stage_a(0, 0);
  load_b(0);
  write_b(0);

  for (int it = 0; it < NIT; ++it) {
    __syncthreads();                       // buf ready (vmcnt drain is cheap:
    const int nx = it + 1;                 // its loads were issued last iter)
    if (nx < NIT) { stage_a(nx, buf ^ 1); load_b(nx); }

    #pragma unroll
    for (int ks = 0; ks < 2; ++ks) {
      short8 af[4], bfr[4];
      const int sl = ((ks * 4 + lq) ^ rsw) * 8;
      #pragma unroll
      for (int mi = 0; mi < 4; ++mi)
        af[mi] = *(const short8*)&As[buf][(wm + mi * 16 + lr) * 64 + sl];
      #pragma unroll
      for (int ni = 0; ni < 4; ++ni)
        bfr[ni] = *(const short8*)&Bs[buf][(wn + ni * 16 + lr) * 64 + sl];
      #pragma unroll
      for (int mi = 0; mi < 4; ++mi)
        #pragma unroll
        for (int ni = 0; ni < 4; ++ni)
          acc[mi][ni] = __builtin_amdgcn_mfma_f32_16x16x32_bf16(af[mi], bfr[ni],
                                                                acc[mi][ni], 0, 0, 0);
    }

    if (nx < NIT) write_b(buf ^ 1);

    if (it < 64) {
      if ((it & 15) == 15) {               // end of d-slice: scale + b_d fold
        const int d = d0 + (it >> 4);
        float bdv[4];
        #pragma unroll
        for (int ni = 0; ni < 4; ++ni)
          bdv[ni] = bd[(size_t)d * O_ + bn + wn + ni * 16 + lr];
        #pragma unroll
        for (int mi = 0; mi < 4; ++mi)
          #pragma unroll
          for (int r = 0; r < 4; ++r) {
            const float sc = inp[(size_t)(bm + wm + mi * 16 + lq * 4 + r) * D_ + d];
            #pragma unroll
            for (int ni = 0; ni < 4; ++ni)
              run[mi][ni][r] += sc * (acc[mi][ni][r] + bdv[ni]);
          }
        #pragma unroll
        for (int mi = 0; mi < 4; ++mi)
          #pragma unroll
          for (int ni = 0; ni < 4; ++ni) acc[mi][ni] = f32x4{0.f, 0.f, 0.f, 0.f};
      }
    } else if (it == NIT - 1) {            // end of comp_b chunk (scale = 1)
      float bbv[4] = {0.f, 0.f, 0.f, 0.f};
      if (y == 0) {
        #pragma unroll
        for (int ni = 0; ni < 4; ++ni)
          bbv[ni] = bbias[bn + wn + ni * 16 + lr];
      }
      #pragma unroll
      for (int mi = 0; mi < 4; ++mi)
        #pragma unroll
        for (int ni = 0; ni < 4; ++ni)
          #pragma unroll
          for (int r = 0; r < 4; ++r)
            run[mi][ni][r] += acc[mi][ni][r] + bbv[ni];
    }
    buf ^= 1;
  }

  #pragma unroll
  for (int mi = 0; mi < 4; ++mi)
    #pragma unroll
    for (int ni = 0; ni < 4; ++ni)
      #pragma unroll
      for (int r = 0; r < 4; ++r) {
        int row = bm + wm + mi * 16 + lq * 4 + r;
        int col = bn + wn + ni * 16 + lr;
        atomicAdd(out + (size_t)row * O_ + col, run[mi][ni][r]);
      }
}

extern "C" void kernel_launch(void* const* d_in, const int* in_sizes, int n_in,
                              void* d_out, int out_size, void* d_ws, size_t ws_size,
                              hipStream_t stream) {
  const float* input = (const float*)d_in[0];   // [512,256]
  const float* nanf  = (const float*)d_in[1];   // [512,256]
  const float* W_in  = (const float*)d_in[3];   // [512,256]
  const float* b_in  = (const float*)d_in[4];
  const float* W_h1  = (const float*)d_in[5];   // [1024,512]
  const float* b_h1  = (const float*)d_in[6];
  const float* W_h2  = (const float*)d_in[7];   // [1024,1024]
  const float* b_h2  = (const float*)d_in[8];
  const float* W_d   = (const float*)d_in[9];   // [65536,1024]
  const float* b_d   = (const float*)d_in[10];  // [65536]
  const float* W_b   = (const float*)d_in[11];  // [256,1024]
  const float* b_b   = (const float*)d_in[12];  // [256]
  float* out = (float*)d_out;                   // [512,256]

  float* x0 = (float*)d_ws;                     // [512,512]   1 MB
  float* x1 = x0 + 512 * 512;                   // [512,1024]  2 MB
  float* x2 = x1 + 512 * 1024;                  // [512,1024]  2 MB
  ushort_t* x2b = (ushort_t*)(x2 + 512 * 1024); // [512,1024] bf16, 1 MB (ws >= 6 MB)

  // out := 0 (everything below atomicAdds into it)
  zero_out<<<128, 256, 0, stream>>>(out);
  // Stage A: MLP (~2 GFLOP, serial-dependent)
  gemm_bt64<1><<<dim3(512 / 64, 512 / 64), 256, 0, stream>>>(nanf, W_in, b_in, x0, 512, 512, 256);
  gemm_bt64<1><<<dim3(1024 / 64, 512 / 64), 256, 0, stream>>>(x0, W_h1, b_h1, x1, 512, 1024, 512);
  gemm_bt64<1><<<dim3(1024 / 64, 512 / 64), 256, 0, stream>>>(x1, W_h2, b_h2, x2, 512, 1024, 1024);
  cvt_f32_bf16<<<256, 256, 0, stream>>>(x2, x2b, 512 * 1024 / 8);
  // Stage B: fused bilinear + comp_b + bias_d + b_b (HBM floor: 256 MB W_d)
  stage_b3<<<dim3(8, 64), 256, 0, stream>>>(x2b, input, W_d, b_d, W_b, b_b, out);
}